// Round 11
// baseline (210.809 us; speedup 1.0000x reference)
//
#include <hip/hip_runtime.h>

namespace {

constexpr int BATCH = 256;
constexpr int DCAPS = 10;
constexpr int PCAPS = 1152;
constexpr int ODIM  = 16;
constexpr int IDIM  = 8;
constexpr float EPS_ = 1e-7f;

constexpr int BPG = 2;               // b's unrolled per 16-lane group
constexpr int GPB = 16;              // groups per 256-thread block
constexpr int BT  = GPB * BPG;       // 32 b's per block
constexpr int NBB = BATCH / BT;      // 8
constexpr int SDO = BATCH * DCAPS * ODIM;     // 40960
constexpr int WSZ = DCAPS * PCAPS * ODIM * IDIM;  // 1474560 floats
constexpr float LOG2E = 1.44269504088896f;

// 16-lane row sum via DPP rotate-reduce (VALU pipe; no LDS traffic).
__device__ __forceinline__ float rsum16(float v)
{
    v += __int_as_float(__builtin_amdgcn_update_dpp(
        0, __float_as_int(v), 0x121, 0xF, 0xF, true));   // row_ror:1
    v += __int_as_float(__builtin_amdgcn_update_dpp(
        0, __float_as_int(v), 0x122, 0xF, 0xF, true));   // row_ror:2
    v += __int_as_float(__builtin_amdgcn_update_dpp(
        0, __float_as_int(v), 0x124, 0xF, 0xF, true));   // row_ror:4
    v += __int_as_float(__builtin_amdgcn_update_dpp(
        0, __float_as_int(v), 0x128, 0xF, 0xF, true));   // row_ror:8
    return v;
}

__device__ __forceinline__ float dot8(const float4& wa, const float4& wb,
                                      const float4& xa, const float4& xb)
{
    float acc = wa.x * xa.x;
    acc = fmaf(wa.y, xa.y, acc);
    acc = fmaf(wa.z, xa.z, acc);
    acc = fmaf(wa.w, xa.w, acc);
    acc = fmaf(wb.x, xb.x, acc);
    acc = fmaf(wb.y, xb.y, acc);
    acc = fmaf(wb.z, xb.z, acc);
    acc = fmaf(wb.w, xb.w, acc);
    return acc;
}

// One-time W repack [D,P,O,I] -> [P,D,O,I] (5.9 MB). Dest-coalesced writes;
// reads are d-strided 8B gathers served by L2/L3. Enables static-immediate
// W addressing in route (d*512B < 8192 imm range): kills per-d 64-bit
// address VALU, R8's largest parasitic instruction class.
__global__ __launch_bounds__(256)
void repack_kernel(const float* __restrict__ W, float* __restrict__ Wp)
{
    const int k  = blockIdx.x * 256 + threadIdx.x;   // float4 id (368640 total)
    const int i4 = k & 1;
    const int o  = (k >> 1) & 15;
    const int pd = k >> 5;
    const int d  = pd % DCAPS;
    const int p  = pd / DCAPS;
    reinterpret_cast<float4*>(Wp)[k] =
        reinterpret_cast<const float4*>(W)[
            ((((size_t)d * PCAPS + p) * ODIM + o) << 1) + i4];
}

// Routing pass. Lane = o, 16-lane group = 2 b's, per-lane-DISTINCT W reads
// (R6/R7 lesson: broadcast W wastes 32-64x operand return bandwidth).
// PACKED: W is [P,D,O,I] -> one base addr per p, 20 loads at imm offsets.
// No LDS, no barriers, no atomics. launch_bounds (256,4): VGPR cap 128
// (R2 lesson: tighter cap spills -> WRITE_SIZE balloons; must stay ~31MB).
template <int NV, int NPBLK, bool PACKED>
__global__ __launch_bounds__(256, 4)
void route_kernel(const float* __restrict__ x, const float* __restrict__ Wp,
                  const float* __restrict__ v0, const float* __restrict__ v1,
                  float* __restrict__ part)
{
    constexpr int PPB = PCAPS / NPBLK;
    const int tid  = threadIdx.x;
    const int g    = tid >> 4;            // 16-lane group
    const int o    = tid & 15;            // output dim (lane)
    const int pBlk = blockIdx.x % NPBLK;  // NPBLK%8==0 -> pBlk%8 = XCD: all 8
    const int bBlk = blockIdx.x / NPBLK;  // bBlk copies of a pBlk share one L2
    const int b0   = bBlk * BT + g * BPG;
    const int p0   = pBlk * PPB;

    // preload v (uv(v0)+uv(v1) = uv(v0+v1)), pre-scaled by log2(e) for exp2
    float vr[BPG][DCAPS];
    if constexpr (NV >= 1) {
#pragma unroll
        for (int bb = 0; bb < BPG; ++bb)
#pragma unroll
            for (int d = 0; d < DCAPS; ++d) {
                float t = v0[((size_t)(b0 + bb) * DCAPS + d) * ODIM + o];
                if constexpr (NV == 2)
                    t += v1[((size_t)(b0 + bb) * DCAPS + d) * ODIM + o];
                vr[bb][d] = t * LOG2E;
            }
    }

    float s_acc[BPG][DCAPS];
#pragma unroll
    for (int bb = 0; bb < BPG; ++bb)
#pragma unroll
        for (int d = 0; d < DCAPS; ++d) s_acc[bb][d] = 0.f;

    for (int pp = 0; pp < PPB; ++pp) {
        const int p = p0 + pp;

        // x for both b's: group-uniform 16B loads (L1 broadcast)
        float4 xa[BPG], xb[BPG];
#pragma unroll
        for (int bb = 0; bb < BPG; ++bb) {
            const float4* xp = reinterpret_cast<const float4*>(
                x + ((size_t)(b0 + bb) * PCAPS + p) * IDIM);
            xa[bb] = xp[0];
            xb[bb] = xp[1];
        }

        // u_hat: one W fragment load serves BPG b's
        float uh[BPG][DCAPS];
        if constexpr (PACKED) {
            // single 64-bit base; d indexes via STATIC imm offsets (d*512B)
            const float* wbase = Wp + (size_t)p * (DCAPS * ODIM * IDIM)
                                    + o * IDIM;
#pragma unroll
            for (int d = 0; d < DCAPS; ++d) {
                const float4* wv = reinterpret_cast<const float4*>(
                    wbase + d * (ODIM * IDIM));
                const float4 wa = wv[0];
                const float4 wb = wv[1];
#pragma unroll
                for (int bb = 0; bb < BPG; ++bb)
                    uh[bb][d] = dot8(wa, wb, xa[bb], xb[bb]);
            }
        } else {
#pragma unroll
            for (int d = 0; d < DCAPS; ++d) {
                const float4* wv = reinterpret_cast<const float4*>(
                    Wp + (((size_t)d * PCAPS + p) * ODIM + o) * IDIM);
                const float4 wa = wv[0];
                const float4 wb = wv[1];
#pragma unroll
                for (int bb = 0; bb < BPG; ++bb)
                    uh[bb][d] = dot8(wa, wb, xa[bb], xb[bb]);
            }
        }

        if constexpr (NV == 0) {
#pragma unroll
            for (int bb = 0; bb < BPG; ++bb)
#pragma unroll
                for (int d = 0; d < DCAPS; ++d)
                    s_acc[bb][d] = fmaf(0.1f, uh[bb][d], s_acc[bb][d]);
        } else {
            // softmax over d; no max-subtraction (|logit| < ~0.5: W ~ 0.01)
            float e[BPG][DCAPS];
            float den[BPG];
#pragma unroll
            for (int bb = 0; bb < BPG; ++bb) den[bb] = 0.f;
#pragma unroll
            for (int bb = 0; bb < BPG; ++bb)
#pragma unroll
                for (int d = 0; d < DCAPS; ++d) {
                    const float l = rsum16(uh[bb][d] * vr[bb][d]);
                    const float t = exp2f(l);
                    e[bb][d] = t;
                    den[bb] += t;
                }
#pragma unroll
            for (int bb = 0; bb < BPG; ++bb) {
                const float inv = 1.0f / den[bb];
#pragma unroll
                for (int d = 0; d < DCAPS; ++d)
                    s_acc[bb][d] = fmaf(e[bb][d] * inv, uh[bb][d], s_acc[bb][d]);
            }
        }
    }

    // partial store: part[pBlk][b][d][o] -- 16 lanes write contiguous 64B
#pragma unroll
    for (int bb = 0; bb < BPG; ++bb)
#pragma unroll
        for (int d = 0; d < DCAPS; ++d)
            part[((size_t)pBlk * BATCH + (b0 + bb)) * (DCAPS * ODIM)
                 + d * ODIM + o] = s_acc[bb][d];
}

// Sum NP chunk-partials then squash. 320 blocks x 256 threads:
// thread = (unit u, chunk-group cg, float4-quarter q); 64B coalesced reads.
template <int NP>
__global__ __launch_bounds__(256)
void squash_kernel(const float* __restrict__ part, float* __restrict__ out)
{
    constexpr int CPC = NP / 8;
    const int tid = threadIdx.x;
    const int u   = tid >> 5;            // 0..7 unit within block
    const int l   = tid & 31;
    const int cg  = l >> 2;              // 0..7 chunk group
    const int q   = l & 3;               // float4 quarter
    const int gu  = blockIdx.x * 8 + u;  // global unit = b*DCAPS + d

    float4 acc = make_float4(0, 0, 0, 0);
    for (int k = 0; k < CPC; ++k) {
        const int c = cg * CPC + k;
        const float4 p4 = reinterpret_cast<const float4*>(
            part + (size_t)c * SDO + (size_t)gu * ODIM)[q];
        acc.x += p4.x; acc.y += p4.y; acc.z += p4.z; acc.w += p4.w;
    }

    __shared__ float4 sred[8][8][4];
    __shared__ float4 sfin[8][4];
    __shared__ float  nrm[8][4];
    __shared__ float  sscale[8];
    sred[u][cg][q] = acc;
    __syncthreads();

    if (cg == 0) {
        float4 s = sred[u][0][q];
#pragma unroll
        for (int c2 = 1; c2 < 8; ++c2) {
            const float4 t = sred[u][c2][q];
            s.x += t.x; s.y += t.y; s.z += t.z; s.w += t.w;
        }
        sfin[u][q] = s;
        nrm[u][q]  = s.x * s.x + s.y * s.y + s.z * s.z + s.w * s.w;
    }
    __syncthreads();
    if (l == 0) {
        const float sq = nrm[u][0] + nrm[u][1] + nrm[u][2] + nrm[u][3];
        sscale[u] = (sq / (1.0f + sq)) / sqrtf(sq + EPS_);
    }
    __syncthreads();
    if (cg == 0) {
        float4 s = sfin[u][q];
        const float sc = sscale[u];
        s.x *= sc; s.y *= sc; s.z *= sc; s.w *= sc;
        reinterpret_cast<float4*>(out)[(size_t)gu * 4 + q] = s;
    }
}

template <int NPBLK, bool PACKED>
void run_all(const float* x, const float* W, const float* Wp,
             float* v0, float* v1, float* part, float* out, hipStream_t stream)
{
    const dim3 blk(256);
    const dim3 rgrid(NPBLK * NBB);
    const dim3 sgrid(BATCH * DCAPS / 8);   // 320
    const float* Wk = PACKED ? Wp : W;

    route_kernel<0, NPBLK, PACKED><<<rgrid, blk, 0, stream>>>(x, Wk, nullptr, nullptr, part);
    squash_kernel<NPBLK><<<sgrid, blk, 0, stream>>>(part, v0);

    route_kernel<1, NPBLK, PACKED><<<rgrid, blk, 0, stream>>>(x, Wk, v0, nullptr, part);
    squash_kernel<NPBLK><<<sgrid, blk, 0, stream>>>(part, v1);

    route_kernel<2, NPBLK, PACKED><<<rgrid, blk, 0, stream>>>(x, Wk, v0, v1, part);
    squash_kernel<NPBLK><<<sgrid, blk, 0, stream>>>(part, out);
}

} // namespace

extern "C" void kernel_launch(void* const* d_in, const int* in_sizes, int n_in,
                              void* d_out, int out_size, void* d_ws, size_t ws_size,
                              hipStream_t stream)
{
    const float* x = (const float*)d_in[0];   // [256, 1152, 8]
    const float* W = (const float*)d_in[1];   // [1, 10, 1152, 16, 8]
    float* out = (float*)d_out;               // [256, 10, 16]

    float* v0   = (float*)d_ws;
    float* v1   = v0 + SDO;
    float* Wp   = v1 + SDO;
    float* part = Wp + WSZ;

    const size_t needA = ((size_t)2 * SDO + WSZ + (size_t)192 * SDO) * sizeof(float); // 37.7MB
    const size_t needB = ((size_t)2 * SDO + WSZ + (size_t)128 * SDO) * sizeof(float); // 27.2MB

    if (ws_size >= needA) {
        repack_kernel<<<dim3(WSZ / 4 / 256), dim3(256), 0, stream>>>(W, Wp);
        run_all<192, true>(x, W, Wp, v0, v1, part, out, stream);   // grid 1536: 6 blk/CU
    } else if (ws_size >= needB) {
        repack_kernel<<<dim3(WSZ / 4 / 256), dim3(256), 0, stream>>>(W, Wp);
        run_all<128, true>(x, W, Wp, v0, v1, part, out, stream);
    } else {
        // no room for Wp: R8-proven unpacked path (part directly after v1)
        run_all<128, false>(x, W, W, v0, v1, Wp, out, stream);
    }
}

// Round 12
// 188.688 us; speedup vs baseline: 1.1172x; 1.1172x over previous
//
#include <hip/hip_runtime.h>

namespace {

constexpr int BATCH = 256;
constexpr int DCAPS = 10;
constexpr int PCAPS = 1152;
constexpr int ODIM  = 16;
constexpr int IDIM  = 8;
constexpr float EPS_ = 1e-7f;

constexpr int BPG = 4;               // b's per 16-lane group (W reg reused 4x)
constexpr int GPB = 16;              // groups per 256-thread block
constexpr int BT  = GPB * BPG;       // 64 b's per block
constexpr int NBB = BATCH / BT;      // 4
constexpr int SDO = BATCH * DCAPS * ODIM;     // 40960
constexpr int WSZ = DCAPS * PCAPS * ODIM * IDIM;  // 1474560 floats
constexpr float LOG2E = 1.44269504088896f;

// 16-lane row sum via DPP rotate-reduce (VALU pipe; no LDS traffic).
__device__ __forceinline__ float rsum16(float v)
{
    v += __int_as_float(__builtin_amdgcn_update_dpp(
        0, __float_as_int(v), 0x121, 0xF, 0xF, true));   // row_ror:1
    v += __int_as_float(__builtin_amdgcn_update_dpp(
        0, __float_as_int(v), 0x122, 0xF, 0xF, true));   // row_ror:2
    v += __int_as_float(__builtin_amdgcn_update_dpp(
        0, __float_as_int(v), 0x124, 0xF, 0xF, true));   // row_ror:4
    v += __int_as_float(__builtin_amdgcn_update_dpp(
        0, __float_as_int(v), 0x128, 0xF, 0xF, true));   // row_ror:8
    return v;
}

__device__ __forceinline__ float dot8(const float4& wa, const float4& wb,
                                      const float4& xa, const float4& xb)
{
    float acc = wa.x * xa.x;
    acc = fmaf(wa.y, xa.y, acc);
    acc = fmaf(wa.z, xa.z, acc);
    acc = fmaf(wa.w, xa.w, acc);
    acc = fmaf(wb.x, xb.x, acc);
    acc = fmaf(wb.y, xb.y, acc);
    acc = fmaf(wb.z, xb.z, acc);
    acc = fmaf(wb.w, xb.w, acc);
    return acc;
}

// One-time W repack [D,P,O,I] -> [P,D,O,I] (5.9 MB): enables single-base +
// static-imm-offset W addressing in route (d*512B < 8192 imm range).
__global__ __launch_bounds__(256)
void repack_kernel(const float* __restrict__ W, float* __restrict__ Wp)
{
    const int k  = blockIdx.x * 256 + threadIdx.x;   // float4 id (368640 total)
    const int i4 = k & 1;
    const int o  = (k >> 1) & 15;
    const int pd = k >> 5;
    const int d  = pd % DCAPS;
    const int p  = pd / DCAPS;
    reinterpret_cast<float4*>(Wp)[k] =
        reinterpret_cast<const float4*>(W)[
            ((((size_t)d * PCAPS + p) * ODIM + o) << 1) + i4];
}

// Routing pass. Lane = o, 16-lane group = FOUR b's (BPG=4).
// R11 post-mortem: pass0==pass2 (half the VALU, same time) => load-path
// bound, and no bandwidth tier saturated => per-wave operand delivery is
// the limiter. BPG 2->4 doubles FMA per delivered W byte (0.43->0.73
// FMA/B) and halves total wave-iters. Live set ~175 VGPR =>
// launch_bounds(256,2): cap 256, 2 waves/SIMD (R8->R11: wave count beyond
// ~2/SIMD was not the lever). R2 lesson: if WRITE_SIZE >> 20.5MB, it's
// spilling -- back off BPG.
template <int NV, int NPBLK, bool PACKED>
__global__ __launch_bounds__(256, 2)
void route_kernel(const float* __restrict__ x, const float* __restrict__ Wp,
                  const float* __restrict__ v0, const float* __restrict__ v1,
                  float* __restrict__ part)
{
    constexpr int PPB = PCAPS / NPBLK;
    const int tid  = threadIdx.x;
    const int g    = tid >> 4;            // 16-lane group
    const int o    = tid & 15;            // output dim (lane)
    const int pBlk = blockIdx.x % NPBLK;  // NPBLK%8==0 -> same-pBlk blocks on 1 XCD
    const int bBlk = blockIdx.x / NPBLK;
    const int b0   = bBlk * BT + g * BPG;
    const int p0   = pBlk * PPB;

    // preload v (uv(v0)+uv(v1) = uv(v0+v1)), pre-scaled by log2(e) for exp2
    float vr[BPG][DCAPS];
    if constexpr (NV >= 1) {
#pragma unroll
        for (int bb = 0; bb < BPG; ++bb)
#pragma unroll
            for (int d = 0; d < DCAPS; ++d) {
                float t = v0[((size_t)(b0 + bb) * DCAPS + d) * ODIM + o];
                if constexpr (NV == 2)
                    t += v1[((size_t)(b0 + bb) * DCAPS + d) * ODIM + o];
                vr[bb][d] = t * LOG2E;
            }
    }

    float s_acc[BPG][DCAPS];
#pragma unroll
    for (int bb = 0; bb < BPG; ++bb)
#pragma unroll
        for (int d = 0; d < DCAPS; ++d) s_acc[bb][d] = 0.f;

    for (int pp = 0; pp < PPB; ++pp) {
        const int p = p0 + pp;

        // x for the 4 b's: group-uniform 16B loads (L1 broadcast)
        float4 xa[BPG], xb[BPG];
#pragma unroll
        for (int bb = 0; bb < BPG; ++bb) {
            const float4* xp = reinterpret_cast<const float4*>(
                x + ((size_t)(b0 + bb) * PCAPS + p) * IDIM);
            xa[bb] = xp[0];
            xb[bb] = xp[1];
        }

        // u_hat: one W fragment load feeds 4 b's (the BPG lever)
        float uh[BPG][DCAPS];
        if constexpr (PACKED) {
            const float* wbase = Wp + (size_t)p * (DCAPS * ODIM * IDIM)
                                    + o * IDIM;
#pragma unroll
            for (int d = 0; d < DCAPS; ++d) {
                const float4* wv = reinterpret_cast<const float4*>(
                    wbase + d * (ODIM * IDIM));
                const float4 wa = wv[0];
                const float4 wb = wv[1];
#pragma unroll
                for (int bb = 0; bb < BPG; ++bb)
                    uh[bb][d] = dot8(wa, wb, xa[bb], xb[bb]);
            }
        } else {
#pragma unroll
            for (int d = 0; d < DCAPS; ++d) {
                const float4* wv = reinterpret_cast<const float4*>(
                    Wp + (((size_t)d * PCAPS + p) * ODIM + o) * IDIM);
                const float4 wa = wv[0];
                const float4 wb = wv[1];
#pragma unroll
                for (int bb = 0; bb < BPG; ++bb)
                    uh[bb][d] = dot8(wa, wb, xa[bb], xb[bb]);
            }
        }

        if constexpr (NV == 0) {
#pragma unroll
            for (int bb = 0; bb < BPG; ++bb)
#pragma unroll
                for (int d = 0; d < DCAPS; ++d)
                    s_acc[bb][d] = fmaf(0.1f, uh[bb][d], s_acc[bb][d]);
        } else {
            // softmax over d; no max-subtraction (|logit| < ~0.5: W ~ 0.01)
            float e[BPG][DCAPS];
            float den[BPG];
#pragma unroll
            for (int bb = 0; bb < BPG; ++bb) den[bb] = 0.f;
#pragma unroll
            for (int bb = 0; bb < BPG; ++bb)
#pragma unroll
                for (int d = 0; d < DCAPS; ++d) {
                    const float l = rsum16(uh[bb][d] * vr[bb][d]);
                    const float t = exp2f(l);
                    e[bb][d] = t;
                    den[bb] += t;
                }
#pragma unroll
            for (int bb = 0; bb < BPG; ++bb) {
                const float inv = 1.0f / den[bb];
#pragma unroll
                for (int d = 0; d < DCAPS; ++d)
                    s_acc[bb][d] = fmaf(e[bb][d] * inv, uh[bb][d], s_acc[bb][d]);
            }
        }
    }

    // partial store: part[pBlk][b][d][o] -- 16 lanes write contiguous 64B
#pragma unroll
    for (int bb = 0; bb < BPG; ++bb)
#pragma unroll
        for (int d = 0; d < DCAPS; ++d)
            part[((size_t)pBlk * BATCH + (b0 + bb)) * (DCAPS * ODIM)
                 + d * ODIM + o] = s_acc[bb][d];
}

// Sum NP chunk-partials then squash. 320 blocks x 256 threads:
// thread = (unit u, chunk-group cg, float4-quarter q); 64B coalesced reads.
template <int NP>
__global__ __launch_bounds__(256)
void squash_kernel(const float* __restrict__ part, float* __restrict__ out)
{
    constexpr int CPC = NP / 8;
    const int tid = threadIdx.x;
    const int u   = tid >> 5;            // 0..7 unit within block
    const int l   = tid & 31;
    const int cg  = l >> 2;              // 0..7 chunk group
    const int q   = l & 3;               // float4 quarter
    const int gu  = blockIdx.x * 8 + u;  // global unit = b*DCAPS + d

    float4 acc = make_float4(0, 0, 0, 0);
    for (int k = 0; k < CPC; ++k) {
        const int c = cg * CPC + k;
        const float4 p4 = reinterpret_cast<const float4*>(
            part + (size_t)c * SDO + (size_t)gu * ODIM)[q];
        acc.x += p4.x; acc.y += p4.y; acc.z += p4.z; acc.w += p4.w;
    }

    __shared__ float4 sred[8][8][4];
    __shared__ float4 sfin[8][4];
    __shared__ float  nrm[8][4];
    __shared__ float  sscale[8];
    sred[u][cg][q] = acc;
    __syncthreads();

    if (cg == 0) {
        float4 s = sred[u][0][q];
#pragma unroll
        for (int c2 = 1; c2 < 8; ++c2) {
            const float4 t = sred[u][c2][q];
            s.x += t.x; s.y += t.y; s.z += t.z; s.w += t.w;
        }
        sfin[u][q] = s;
        nrm[u][q]  = s.x * s.x + s.y * s.y + s.z * s.z + s.w * s.w;
    }
    __syncthreads();
    if (l == 0) {
        const float sq = nrm[u][0] + nrm[u][1] + nrm[u][2] + nrm[u][3];
        sscale[u] = (sq / (1.0f + sq)) / sqrtf(sq + EPS_);
    }
    __syncthreads();
    if (cg == 0) {
        float4 s = sfin[u][q];
        const float sc = sscale[u];
        s.x *= sc; s.y *= sc; s.z *= sc; s.w *= sc;
        reinterpret_cast<float4*>(out)[(size_t)gu * 4 + q] = s;
    }
}

template <int NPBLK, bool PACKED>
void run_all(const float* x, const float* W, const float* Wp,
             float* v0, float* v1, float* part, float* out, hipStream_t stream)
{
    const dim3 blk(256);
    const dim3 rgrid(NPBLK * NBB);         // 512: exactly 2 blocks/CU resident
    const dim3 sgrid(BATCH * DCAPS / 8);   // 320
    const float* Wk = PACKED ? Wp : W;

    route_kernel<0, NPBLK, PACKED><<<rgrid, blk, 0, stream>>>(x, Wk, nullptr, nullptr, part);
    squash_kernel<NPBLK><<<sgrid, blk, 0, stream>>>(part, v0);

    route_kernel<1, NPBLK, PACKED><<<rgrid, blk, 0, stream>>>(x, Wk, v0, nullptr, part);
    squash_kernel<NPBLK><<<sgrid, blk, 0, stream>>>(part, v1);

    route_kernel<2, NPBLK, PACKED><<<rgrid, blk, 0, stream>>>(x, Wk, v0, v1, part);
    squash_kernel<NPBLK><<<sgrid, blk, 0, stream>>>(part, out);
}

} // namespace

extern "C" void kernel_launch(void* const* d_in, const int* in_sizes, int n_in,
                              void* d_out, int out_size, void* d_ws, size_t ws_size,
                              hipStream_t stream)
{
    const float* x = (const float*)d_in[0];   // [256, 1152, 8]
    const float* W = (const float*)d_in[1];   // [1, 10, 1152, 16, 8]
    float* out = (float*)d_out;               // [256, 10, 16]

    float* v0   = (float*)d_ws;
    float* v1   = v0 + SDO;
    float* Wp   = v1 + SDO;
    float* part = Wp + WSZ;

    const size_t needP = ((size_t)2 * SDO + WSZ + (size_t)128 * SDO) * sizeof(float); // 27.2MB

    if (ws_size >= needP) {
        repack_kernel<<<dim3(WSZ / 4 / 256), dim3(256), 0, stream>>>(W, Wp);
        run_all<128, true>(x, W, Wp, v0, v1, part, out, stream);
    } else {
        // no room for Wp: unpacked W, partials directly after v1 (21.3MB, proven)
        run_all<128, false>(x, W, W, v0, v1, Wp, out, stream);
    }
}

// Round 13
// 165.332 us; speedup vs baseline: 1.2751x; 1.1413x over previous
//
#include <hip/hip_runtime.h>
#include <hip/hip_bf16.h>

namespace {

constexpr int BATCH = 256;
constexpr int DCAPS = 10;
constexpr int PCAPS = 1152;
constexpr int ODIM  = 16;
constexpr int IDIM  = 8;
constexpr float EPS_ = 1e-7f;
constexpr int SDO = BATCH * DCAPS * ODIM;          // 40960
constexpr float LOG2E = 1.44269504088896f;

typedef __attribute__((ext_vector_type(8))) short short8_t;  // 8 bf16 (4 VGPR)
typedef __attribute__((ext_vector_type(4))) float f32x4;

__device__ __forceinline__ ushort f2bf_bits(float f)
{
    __hip_bfloat16 h = __float2bfloat16(f);
    return *reinterpret_cast<ushort*>(&h);
}
__device__ __forceinline__ float bfbits2f(ushort u)
{
    __hip_bfloat16 h = *reinterpret_cast<__hip_bfloat16*>(&u);
    return __bfloat162float(h);
}

// Split fp32 -> bf16 hi + bf16 lo(residual). Vectorized x4.
__global__ __launch_bounds__(256)
void split_kernel(const float* __restrict__ src, ushort* __restrict__ hi,
                  ushort* __restrict__ lo, int n4)
{
    const int i = blockIdx.x * 256 + threadIdx.x;
    if (i >= n4) return;
    const float4 w = reinterpret_cast<const float4*>(src)[i];
    ushort4 h, l;
    h.x = f2bf_bits(w.x); l.x = f2bf_bits(w.x - bfbits2f(h.x));
    h.y = f2bf_bits(w.y); l.y = f2bf_bits(w.y - bfbits2f(h.y));
    h.z = f2bf_bits(w.z); l.z = f2bf_bits(w.z - bfbits2f(h.z));
    h.w = f2bf_bits(w.w); l.w = f2bf_bits(w.w - bfbits2f(h.w));
    reinterpret_cast<ushort4*>(hi)[i] = h;
    reinterpret_cast<ushort4*>(lo)[i] = l;
}

// ===================== MFMA route =====================
// Per (d, 4p-tile): D[o, (b,p)] = sum_{p',i} W[d,p',o,i] * x[b,p,i]
//   A[m=o, k=(p'*8+i)]      = W[d, p0+p', o, i]           (dense)
//   B[k=(p'*8+i), n=(bs,ps)] = x[b0+bs, p0+ps, i] if p'==ps else 0
// Fragment maps (16x16x32): A/B: lane row/col = l&15, k = (l>>4)*8+j;
// D: col n = l&15, row m = (l>>4)*4 + reg  [guide m89].
// => lane holds fixed (b,p) = l&15 and 4 o's (o = (l>>4)*4+reg) in regs:
// logits are in-lane dot4 + shfl_xor(16,32); exp2 per (d) not (d,p).
// Split-bf16 (hi+lo) x 3 MFMAs => abs err ~1e-6 (fp32-grade).
template <int NV, int NPBLK>
__global__ __launch_bounds__(256, 2)
void route_mfma(const ushort* __restrict__ xh, const ushort* __restrict__ xl,
                const ushort* __restrict__ wh, const ushort* __restrict__ wl,
                const float* __restrict__ v0, const float* __restrict__ v1,
                float* __restrict__ part)
{
    constexpr int PPB = PCAPS / NPBLK;   // 12
    constexpr int TPW = PPB / 4;         // 3 4-p tiles per wave
    const int tid  = threadIdx.x;
    const int l    = tid & 63;
    const int w    = tid >> 6;                 // wave 0..3
    const int pBlk = blockIdx.x % NPBLK;       // fastest: spread over XCDs
    const int bBlk = blockIdx.x / NPBLK;
    const int kgrp = l >> 4;                   // A/B k-group; D o-quarter
    const int n    = l & 15;                   // D col: (bsub, psub)
    const int bsub = n >> 2;
    const int psub = n & 3;
    const int b    = bBlk * 16 + w * 4 + bsub; // this lane's b
    const int o0   = kgrp * 4;                 // this lane's o-quarter

    // vr[d] = (v0 [+ v1])[b][d][o0:o0+4] * LOG2E  (logit dot operand)
    f32x4 vr[DCAPS];
    if constexpr (NV >= 1) {
#pragma unroll
        for (int d = 0; d < DCAPS; ++d) {
            const float4 t = *reinterpret_cast<const float4*>(
                v0 + ((size_t)b * DCAPS + d) * ODIM + o0);
            f32x4 v = {t.x, t.y, t.z, t.w};
            if constexpr (NV == 2) {
                const float4 u = *reinterpret_cast<const float4*>(
                    v1 + ((size_t)b * DCAPS + d) * ODIM + o0);
                v.x += u.x; v.y += u.y; v.z += u.z; v.w += u.w;
            }
            vr[d] = v * LOG2E;
        }
    }

    const f32x4 zero4 = {0.f, 0.f, 0.f, 0.f};
    f32x4 s_acc[DCAPS];
#pragma unroll
    for (int d = 0; d < DCAPS; ++d) s_acc[d] = zero4;

    const bool xact = (kgrp == psub);          // B sparsity: 1/4 lanes carry x

    for (int t = 0; t < TPW; ++t) {
        const int p0 = pBlk * PPB + t * 4;

        // B fragment (x), hi+lo
        short8_t bxh = {0,0,0,0,0,0,0,0};
        short8_t bxl = {0,0,0,0,0,0,0,0};
        if (xact) {
            const size_t xo = ((size_t)b * PCAPS + p0 + psub) * IDIM;
            bxh = *reinterpret_cast<const short8_t*>(xh + xo);
            bxl = *reinterpret_cast<const short8_t*>(xl + xo);
        }

        // u_hat via 3-MFMA split per d
        f32x4 acc[DCAPS];
#pragma unroll
        for (int d = 0; d < DCAPS; ++d) {
            const size_t wo = (((size_t)d * PCAPS + p0 + kgrp) * ODIM + n) * IDIM;
            const short8_t awh = *reinterpret_cast<const short8_t*>(wh + wo);
            const short8_t awl = *reinterpret_cast<const short8_t*>(wl + wo);
            f32x4 a = zero4;
            a = __builtin_amdgcn_mfma_f32_16x16x32_bf16(awh, bxh, a, 0, 0, 0);
            a = __builtin_amdgcn_mfma_f32_16x16x32_bf16(awl, bxh, a, 0, 0, 0);
            a = __builtin_amdgcn_mfma_f32_16x16x32_bf16(awh, bxl, a, 0, 0, 0);
            acc[d] = a;
        }

        if constexpr (NV == 0) {
#pragma unroll
            for (int d = 0; d < DCAPS; ++d) s_acc[d] += 0.1f * acc[d];
        } else {
            // logits: in-lane dot4 + cross-quarter sum (lanes ^16, ^32)
            float e[DCAPS];
            float den = 0.f;
#pragma unroll
            for (int d = 0; d < DCAPS; ++d) {
                const f32x4 pr = acc[d] * vr[d];
                float t2 = pr.x + pr.y + pr.z + pr.w;
                t2 += __shfl_xor(t2, 16);
                t2 += __shfl_xor(t2, 32);
                const float ex = exp2f(t2);
                e[d] = ex;
                den += ex;
            }
            const float inv = 1.0f / den;
#pragma unroll
            for (int d = 0; d < DCAPS; ++d)
                s_acc[d] += (e[d] * inv) * acc[d];
        }
    }

    // fold the 4 psub lanes (l^1, l^2 share (b, o-quarter)), then store
#pragma unroll
    for (int d = 0; d < DCAPS; ++d) {
        f32x4 s = s_acc[d];
        s.x += __shfl_xor(s.x, 1); s.x += __shfl_xor(s.x, 2);
        s.y += __shfl_xor(s.y, 1); s.y += __shfl_xor(s.y, 2);
        s.z += __shfl_xor(s.z, 1); s.z += __shfl_xor(s.z, 2);
        s.w += __shfl_xor(s.w, 1); s.w += __shfl_xor(s.w, 2);
        if (psub == 0) {
            float4 st; st.x = s.x; st.y = s.y; st.z = s.z; st.w = s.w;
            *reinterpret_cast<float4*>(
                part + (((size_t)pBlk * BATCH + b) * DCAPS + d) * ODIM + o0) = st;
        }
    }
}

// ===================== fp32 fallback route (R12-proven) =====================
__device__ __forceinline__ float rsum16(float v)
{
    v += __int_as_float(__builtin_amdgcn_update_dpp(
        0, __float_as_int(v), 0x121, 0xF, 0xF, true));
    v += __int_as_float(__builtin_amdgcn_update_dpp(
        0, __float_as_int(v), 0x122, 0xF, 0xF, true));
    v += __int_as_float(__builtin_amdgcn_update_dpp(
        0, __float_as_int(v), 0x124, 0xF, 0xF, true));
    v += __int_as_float(__builtin_amdgcn_update_dpp(
        0, __float_as_int(v), 0x128, 0xF, 0xF, true));
    return v;
}

__device__ __forceinline__ float dot8(const float4& wa, const float4& wb,
                                      const float4& xa, const float4& xb)
{
    float acc = wa.x * xa.x;
    acc = fmaf(wa.y, xa.y, acc);
    acc = fmaf(wa.z, xa.z, acc);
    acc = fmaf(wa.w, xa.w, acc);
    acc = fmaf(wb.x, xb.x, acc);
    acc = fmaf(wb.y, xb.y, acc);
    acc = fmaf(wb.z, xb.z, acc);
    acc = fmaf(wb.w, xb.w, acc);
    return acc;
}

template <int NV>
__global__ __launch_bounds__(256, 2)
void route_fp32(const float* __restrict__ x, const float* __restrict__ W,
                const float* __restrict__ v0, const float* __restrict__ v1,
                float* __restrict__ part)
{
    constexpr int NPBLK = 128, PPB = 9, BPG = 4, BT = 64;
    const int tid  = threadIdx.x;
    const int g    = tid >> 4;
    const int o    = tid & 15;
    const int pBlk = blockIdx.x % NPBLK;
    const int bBlk = blockIdx.x / NPBLK;
    const int b0   = bBlk * BT + g * BPG;
    const int p0   = pBlk * PPB;

    float vr[BPG][DCAPS];
    if constexpr (NV >= 1) {
#pragma unroll
        for (int bb = 0; bb < BPG; ++bb)
#pragma unroll
            for (int d = 0; d < DCAPS; ++d) {
                float t = v0[((size_t)(b0 + bb) * DCAPS + d) * ODIM + o];
                if constexpr (NV == 2)
                    t += v1[((size_t)(b0 + bb) * DCAPS + d) * ODIM + o];
                vr[bb][d] = t * LOG2E;
            }
    }
    float s_acc[BPG][DCAPS];
#pragma unroll
    for (int bb = 0; bb < BPG; ++bb)
#pragma unroll
        for (int d = 0; d < DCAPS; ++d) s_acc[bb][d] = 0.f;

    for (int pp = 0; pp < PPB; ++pp) {
        const int p = p0 + pp;
        float4 xa[BPG], xb[BPG];
#pragma unroll
        for (int bb = 0; bb < BPG; ++bb) {
            const float4* xp = reinterpret_cast<const float4*>(
                x + ((size_t)(b0 + bb) * PCAPS + p) * IDIM);
            xa[bb] = xp[0]; xb[bb] = xp[1];
        }
        float uh[BPG][DCAPS];
#pragma unroll
        for (int d = 0; d < DCAPS; ++d) {
            const float4* wv = reinterpret_cast<const float4*>(
                W + (((size_t)d * PCAPS + p) * ODIM + o) * IDIM);
            const float4 wa = wv[0];
            const float4 wb = wv[1];
#pragma unroll
            for (int bb = 0; bb < BPG; ++bb)
                uh[bb][d] = dot8(wa, wb, xa[bb], xb[bb]);
        }
        if constexpr (NV == 0) {
#pragma unroll
            for (int bb = 0; bb < BPG; ++bb)
#pragma unroll
                for (int d = 0; d < DCAPS; ++d)
                    s_acc[bb][d] = fmaf(0.1f, uh[bb][d], s_acc[bb][d]);
        } else {
            float e[BPG][DCAPS];
            float den[BPG];
#pragma unroll
            for (int bb = 0; bb < BPG; ++bb) den[bb] = 0.f;
#pragma unroll
            for (int bb = 0; bb < BPG; ++bb)
#pragma unroll
                for (int d = 0; d < DCAPS; ++d) {
                    const float lg = rsum16(uh[bb][d] * vr[bb][d]);
                    const float t = exp2f(lg);
                    e[bb][d] = t; den[bb] += t;
                }
#pragma unroll
            for (int bb = 0; bb < BPG; ++bb) {
                const float inv = 1.0f / den[bb];
#pragma unroll
                for (int d = 0; d < DCAPS; ++d)
                    s_acc[bb][d] = fmaf(e[bb][d] * inv, uh[bb][d], s_acc[bb][d]);
            }
        }
    }
#pragma unroll
    for (int bb = 0; bb < BPG; ++bb)
#pragma unroll
        for (int d = 0; d < DCAPS; ++d)
            part[((size_t)pBlk * BATCH + (b0 + bb)) * (DCAPS * ODIM)
                 + d * ODIM + o] = s_acc[bb][d];
}

// ===================== squash =====================
template <int NP>
__global__ __launch_bounds__(256)
void squash_kernel(const float* __restrict__ part, float* __restrict__ out)
{
    constexpr int CPC = NP / 8;
    const int tid = threadIdx.x;
    const int u   = tid >> 5;
    const int l   = tid & 31;
    const int cg  = l >> 2;
    const int q   = l & 3;
    const int gu  = blockIdx.x * 8 + u;

    float4 acc = make_float4(0, 0, 0, 0);
    for (int k = 0; k < CPC; ++k) {
        const int c = cg * CPC + k;
        const float4 p4 = reinterpret_cast<const float4*>(
            part + (size_t)c * SDO + (size_t)gu * ODIM)[q];
        acc.x += p4.x; acc.y += p4.y; acc.z += p4.z; acc.w += p4.w;
    }
    __shared__ float4 sred[8][8][4];
    __shared__ float4 sfin[8][4];
    __shared__ float  nrm[8][4];
    __shared__ float  sscale[8];
    sred[u][cg][q] = acc;
    __syncthreads();
    if (cg == 0) {
        float4 s = sred[u][0][q];
#pragma unroll
        for (int c2 = 1; c2 < 8; ++c2) {
            const float4 t = sred[u][c2][q];
            s.x += t.x; s.y += t.y; s.z += t.z; s.w += t.w;
        }
        sfin[u][q] = s;
        nrm[u][q]  = s.x * s.x + s.y * s.y + s.z * s.z + s.w * s.w;
    }
    __syncthreads();
    if (l == 0) {
        const float sq = nrm[u][0] + nrm[u][1] + nrm[u][2] + nrm[u][3];
        sscale[u] = (sq / (1.0f + sq)) / sqrtf(sq + EPS_);
    }
    __syncthreads();
    if (cg == 0) {
        float4 s = sfin[u][q];
        const float sc = sscale[u];
        s.x *= sc; s.y *= sc; s.z *= sc; s.w *= sc;
        reinterpret_cast<float4*>(out)[(size_t)gu * 4 + q] = s;
    }
}

} // namespace

extern "C" void kernel_launch(void* const* d_in, const int* in_sizes, int n_in,
                              void* d_out, int out_size, void* d_ws, size_t ws_size,
                              hipStream_t stream)
{
    const float* x = (const float*)d_in[0];   // [256, 1152, 8]
    const float* W = (const float*)d_in[1];   // [1, 10, 1152, 16, 8]
    float* out = (float*)d_out;               // [256, 10, 16]

    constexpr int NPB  = 96;                  // MFMA-path p-blocks
    constexpr int WELT = DCAPS * PCAPS * ODIM * IDIM;   // 1474560
    constexpr int XELT = BATCH * PCAPS * IDIM;          // 2359296

    float* v0 = (float*)d_ws;
    float* v1 = v0 + SDO;
    // MFMA-path layout (f32 slot offsets; all 16B aligned)
    ushort* wh = (ushort*)(v1 + SDO);
    ushort* wl = wh + WELT;
    ushort* xh = wl + WELT;
    ushort* xl = xh + XELT;
    float* partM = (float*)(xl + XELT);

    const size_t needM = ((size_t)2 * SDO + WELT + XELT   // ushort halves*2 = elt f32
                          + (size_t)NPB * SDO) * sizeof(float);   // ~31.4MB

    const dim3 blk(256);
    const dim3 sgrid(BATCH * DCAPS / 8);      // 320

    if (ws_size >= needM) {
        split_kernel<<<dim3((WELT / 4 + 255) / 256), blk, 0, stream>>>(W, wh, wl, WELT / 4);
        split_kernel<<<dim3((XELT / 4 + 255) / 256), blk, 0, stream>>>(x, xh, xl, XELT / 4);

        const dim3 rgrid(NPB * (BATCH / 16)); // 1536
        route_mfma<0, NPB><<<rgrid, blk, 0, stream>>>(xh, xl, wh, wl, nullptr, nullptr, partM);
        squash_kernel<NPB><<<sgrid, blk, 0, stream>>>(partM, v0);

        route_mfma<1, NPB><<<rgrid, blk, 0, stream>>>(xh, xl, wh, wl, v0, nullptr, partM);
        squash_kernel<NPB><<<sgrid, blk, 0, stream>>>(partM, v1);

        route_mfma<2, NPB><<<rgrid, blk, 0, stream>>>(xh, xl, wh, wl, v0, v1, partM);
        squash_kernel<NPB><<<sgrid, blk, 0, stream>>>(partM, out);
    } else {
        // fp32 fallback (R12-proven): partials right after v1 (21.3MB)
        float* partF = v1 + SDO;
        const dim3 rgrid(128 * 4);            // 512
        route_fp32<0><<<rgrid, blk, 0, stream>>>(x, W, nullptr, nullptr, partF);
        squash_kernel<128><<<sgrid, blk, 0, stream>>>(partF, v0);
        route_fp32<1><<<rgrid, blk, 0, stream>>>(x, W, v0, nullptr, partF);
        squash_kernel<128><<<sgrid, blk, 0, stream>>>(partF, v1);
        route_fp32<2><<<rgrid, blk, 0, stream>>>(x, W, v0, v1, partF);
        squash_kernel<128><<<sgrid, blk, 0, stream>>>(partF, out);
    }
}